// Round 12
// baseline (228.236 us; speedup 1.0000x reference)
//
#include <hip/hip_runtime.h>
#include <math.h>

#define N_ROWS (32 * 64 * 64)   // 131072 rows
#define KCODES 1024
#define DIM 64
#define NCHUNK 16               // 64 codes per chunk, 16 KB per chunk (hi+lo)

typedef __attribute__((ext_vector_type(8))) _Float16 f16x8;
typedef __attribute__((ext_vector_type(4))) float f32x4;
typedef unsigned long long u64;
typedef unsigned int u32;

// d_ws layout:
//   0       double loss_sum
//   8       u32 flag_count
//   16      int counts[1024]            (-> 4112) [zeroed]
//   4352    float bn[1024]              exact chain norms
//   8448    float nbs[1024]             1536 + 128*bn (fp32)
//   16384   char Bc[16][16384]          per 64-code chunk, gload-linear order:
//                                       hi [0,8K): off = tt*2048 + ks*1024 + (g*16+cl)*16 + j*2
//                                       lo [8K,16K): same
//   278528  u32 flaglist[N_ROWS]
#define WS_FLAGCNT_OFF 8
#define WS_COUNTS_OFF  16
#define WS_BN_OFF      4352
#define WS_NBS_OFF     8448
#define WS_BC_OFF      16384
#define WS_FLIST_OFF   278528
#define WS_ZERO_BYTES  4112

__device__ inline void gload_lds16(const void* g, void* l) {
    __builtin_amdgcn_global_load_lds(
        (const __attribute__((address_space(1))) unsigned int*)g,
        (__attribute__((address_space(3))) unsigned int*)l,
        16, 0, 0);
}

// ---------- prep: exact bn, C-init consts, 16x16-fragment-order split codes
// B-frag semantics (16x16x32): lane l supplies B[k=(l>>4)*8+j][col=l&15];
// value for code c, k: 256*e[k], hi/lo fp16 split.
__global__ void vq_prep(const float* __restrict__ emb,
                        float* __restrict__ bn,
                        float* __restrict__ nbs,
                        char* __restrict__ Bc) {
    int c = blockIdx.x * 256 + threadIdx.x;   // 4 blocks x 256 = 1024 codes
    const float* e = emb + (size_t)c * DIM;
    float s = 0.f;
#pragma unroll
    for (int d = 0; d < DIM; ++d) s = fmaf(e[d], e[d], s);
    bn[c] = s;
    nbs[c] = fmaf(s, 128.0f, 1536.0f);

    const int ch = c >> 6, tt = (c >> 4) & 3, cl = c & 15;
    char* dst = Bc + (size_t)ch * 16384;
#pragma unroll
    for (int ks = 0; ks < 2; ++ks)
#pragma unroll
        for (int g = 0; g < 4; ++g) {
            f16x8 ph, pl;
#pragma unroll
            for (int j = 0; j < 8; ++j) {
                float v = e[ks * 32 + g * 8 + j] * 256.0f;
                _Float16 hh = (_Float16)v;
                ph[j] = hh;
                pl[j] = (_Float16)(v - (float)hh);
            }
            const int off = tt * 2048 + ks * 1024 + (g * 16 + cl) * 16;
            *(f16x8*)(dst + off)        = ph;
            *(f16x8*)(dst + 8192 + off) = pl;
        }
}

// async copy chunk c into LDS buffer b: 2 x (512 threads x 16B) = 16 KB
#define STAGE(b, c) do {                                                  \
    const char* _g = Bc + (size_t)(c) * 16384 + tid * 16;                 \
    char* _l = &LB[b][(tid >> 6) * 1024];   /* wave-uniform base */       \
    gload_lds16(_g,        _l);                                           \
    gload_lds16(_g + 8192, _l + 8192);                                    \
} while (0)

// ---------- screen: 8-wave blocks, 16 rows/wave via mfma 16x16x32.
// acc = 1536 + 128*bn - 256*dot (positive, guarded) -> u32 bit-min == argmin.
// Small state (acc 4, tracking 12, A-frags 16) -> high occupancy.
__launch_bounds__(512, 4)
__global__ void vq_screen(const float* __restrict__ x,
                          const char* __restrict__ Bc,
                          const float* __restrict__ nbs,
                          const float* __restrict__ emb,
                          float* __restrict__ out,
                          int* __restrict__ counts,
                          double* __restrict__ loss_sum,
                          u32* __restrict__ flagcnt,
                          u32* __restrict__ flaglist) {
    __shared__ __align__(16) char LB[2][16384];

    const int tid  = threadIdx.x;
    const int lane = tid & 63;
    const int wid  = tid >> 6;           // 8 waves x 16 rows = 128 rows/block
    const int cl = lane & 15;            // col slot (codes) / x-row for loads
    const int g  = lane >> 4;            // k-group 0..3
    const int rbase = blockIdx.x * 128 + wid * 16;
    const int myrow = rbase + cl;        // row whose x-elements this lane loads

    // A fragments: lane l, step ks, slot j = -x[myrow][ks*32 + g*8 + j]
    f16x8 ah0, ah1, al0, al1;
    float anp = 0.f;
    {
        const float* xp = x + (size_t)myrow * DIM + g * 8;
#pragma unroll
        for (int ks = 0; ks < 2; ++ks) {
            float4 u0 = *(const float4*)(xp + ks * 32);
            float4 u1 = *(const float4*)(xp + ks * 32 + 4);
            float v[8] = {u0.x, u0.y, u0.z, u0.w, u1.x, u1.y, u1.z, u1.w};
            f16x8 h8, l8;
#pragma unroll
            for (int j = 0; j < 8; ++j) {
                anp = fmaf(v[j], v[j], anp);
                float nv = -v[j];
                _Float16 hh = (_Float16)nv;
                h8[j] = hh;
                l8[j] = (_Float16)(nv - (float)hh);
            }
            if (ks == 0) { ah0 = h8; al0 = l8; }
            else         { ah1 = h8; al1 = l8; }
        }
    }
    // an[row=cl], replicated across the 4 k-groups
    anp += __shfl_xor(anp, 16);
    anp += __shfl_xor(anp, 32);
    const float an = anp;

    u32 best[4], sec[4], bcol[4];
#pragma unroll
    for (int r = 0; r < 4; ++r) {
        best[r] = 0xFFFFFFFFu; sec[r] = 0xFFFFFFFFu; bcol[r] = 0u;
    }

    STAGE(0, 0);
    __syncthreads();

    for (int c = 0; c < NCHUNK; ++c) {
        const int b = c & 1;
        if (c + 1 < NCHUNK) STAGE(b ^ 1, c + 1);   // overlap with compute
        const char* base = LB[b];

#pragma unroll
        for (int tt = 0; tt < 4; ++tt) {
            const float nb = nbs[c * 64 + tt * 16 + cl];   // depends on col only
            f32x4 acc = {nb, nb, nb, nb};
            {
                const int off = tt * 2048 + lane * 16;
                f16x8 vh = *(const f16x8*)(base + off);
                f16x8 vl = *(const f16x8*)(base + 8192 + off);
                acc = __builtin_amdgcn_mfma_f32_16x16x32_f16(ah0, vh, acc, 0, 0, 0);
                acc = __builtin_amdgcn_mfma_f32_16x16x32_f16(ah0, vl, acc, 0, 0, 0);
                acc = __builtin_amdgcn_mfma_f32_16x16x32_f16(al0, vh, acc, 0, 0, 0);
            }
            {
                const int off = tt * 2048 + 1024 + lane * 16;
                f16x8 vh = *(const f16x8*)(base + off);
                f16x8 vl = *(const f16x8*)(base + 8192 + off);
                acc = __builtin_amdgcn_mfma_f32_16x16x32_f16(ah1, vh, acc, 0, 0, 0);
                acc = __builtin_amdgcn_mfma_f32_16x16x32_f16(ah1, vl, acc, 0, 0, 0);
                acc = __builtin_amdgcn_mfma_f32_16x16x32_f16(al1, vh, acc, 0, 0, 0);
            }
            const u32 tl = (u32)(c * 64 + tt * 16 + cl);
#pragma unroll
            for (int r = 0; r < 4; ++r) {
                u32 vb = __float_as_uint(acc[r]);  // positive -> monotone bits
                u32 mx = vb > best[r] ? vb : best[r];
                sec[r] = min(sec[r], mx);
                bool lt = vb < best[r];            // strict: first index wins
                bcol[r] = lt ? tl : bcol[r];
                best[r] = min(best[r], vb);
            }
        }
        __syncthreads();   // next chunk staged + all waves done with buf b
    }

    // reduce across the 16 col-lanes of each k-group (masks 1,2,4,8)
    u64 bp[4];
#pragma unroll
    for (int r = 0; r < 4; ++r) bp[r] = ((u64)best[r] << 32) | bcol[r];
#pragma unroll
    for (int m = 1; m < 16; m <<= 1) {
#pragma unroll
        for (int r = 0; r < 4; ++r) {
            u64 o  = __shfl_xor(bp[r], m);
            u32 os = __shfl_xor(sec[r], m);
            u32 oh = (u32)(o >> 32);
            u32 mh = (u32)(bp[r] >> 32);
            u32 mx = mh > oh ? mh : oh;
            sec[r] = min(min(sec[r], os), mx);
            if (o < bp[r]) bp[r] = o;
        }
    }

    // certify/gather: r-slot r of group g = row g*4+r; 64 lanes write 4 rows
    double dsum = 0.0;
#pragma unroll
    for (int r = 0; r < 4; ++r) {
        const int rowl = g * 4 + r;
        const int grow = rbase + rowl;
        const float bv = __uint_as_float((u32)(bp[r] >> 32));
        const u32 col = (u32)bp[r];
        const float sv = __uint_as_float(sec[r]);
        const float anr = __shfl(an, (lane & 48) | rowl);
        const float gap = sv - bv;
        const float T = fmaf(1e-4f, anr, 0.004f);
        const bool flg = (gap <= T) || (anr < 4.0f) || (anr > 5000.0f);
        if (!flg) {
            float4 q = *(const float4*)(emb + (size_t)col * DIM + cl * 4);
            *(float4*)(out + (size_t)grow * DIM + cl * 4) = q;
            if (cl == 0) {
                atomicAdd(&counts[col], 1);
                // loss identity: dist = an + bn - 2 dot = (acc-1536)/128 + an
                float dist = fmaxf(fmaf(bv - 1536.0f, 0.0078125f, anr), 0.f);
                dsum += (double)dist;
            }
        } else if (cl == 0) {
            u32 idx = atomicAdd(flagcnt, 1u);
            flaglist[idx] = (u32)grow;
        }
    }
    dsum += __shfl_xor(dsum, 16);
    dsum += __shfl_xor(dsum, 32);
    if (lane == 0) atomicAdd(loss_sum, dsum);
}

// ---------- rescan: block-per-flagged-row, exact fp32 argmin (R1 chains)
#define RS_GRID 4096
__launch_bounds__(256)
__global__ void vq_rescan(const float* __restrict__ x,
                          const float* __restrict__ emb,
                          const float* __restrict__ bn,
                          const u32* __restrict__ flagcnt,
                          const u32* __restrict__ flaglist,
                          float* __restrict__ out,
                          int* __restrict__ counts,
                          double* __restrict__ loss_sum) {
    __shared__ float Xs[DIM];
    __shared__ u64 wred[4];
    const u32 n = *flagcnt;
    const int t = threadIdx.x;

    for (u32 i = blockIdx.x; i < n; i += RS_GRID) {
        const int row = (int)flaglist[i];
        if (t < DIM) Xs[t] = x[(size_t)row * DIM + t];
        __syncthreads();

        float an = 0.f;
#pragma unroll
        for (int d = 0; d < DIM; ++d) an = fmaf(Xs[d], Xs[d], an);

        u64 bestp = ~0ull;
#pragma unroll
        for (int cc = 0; cc < 4; ++cc) {
            const int k = cc * 256 + t;
            const float* ek = emb + (size_t)k * DIM;
            float q0 = 0.f, q1 = 0.f, q2 = 0.f, q3 = 0.f;
#pragma unroll
            for (int d = 0; d < DIM; d += 4) {
                float4 ev = *(const float4*)(ek + d);
                q0 = fmaf(Xs[d],     ev.x, q0);
                q1 = fmaf(Xs[d + 1], ev.y, q1);
                q2 = fmaf(Xs[d + 2], ev.z, q2);
                q3 = fmaf(Xs[d + 3], ev.w, q3);
            }
            float dot = (q0 + q1) + (q2 + q3);
            float dist = fmaxf((an + bn[k]) - 2.0f * dot, 0.f);
            u64 p = ((u64)__float_as_uint(dist) << 32) | (u32)k;
            if (p < bestp) bestp = p;
        }
#pragma unroll
        for (int m = 1; m < 64; m <<= 1) {
            u64 o = __shfl_xor(bestp, m);
            if (o < bestp) bestp = o;
        }
        if ((t & 63) == 0) wred[t >> 6] = bestp;
        __syncthreads();
        u64 b = wred[0];
        if (wred[1] < b) b = wred[1];
        if (wred[2] < b) b = wred[2];
        if (wred[3] < b) b = wred[3];
        const int bk = (int)(u32)b;

        if (t < DIM) {
            float qv = emb[(size_t)bk * DIM + t];
            out[(size_t)row * DIM + t] = qv;
            float dx = qv - Xs[t];
            double ds = (double)(dx * dx);
#pragma unroll
            for (int m = 1; m < 64; m <<= 1) ds += __shfl_xor(ds, m);
            if (t == 0) {
                atomicAdd(loss_sum, ds);
                atomicAdd(&counts[bk], 1);
            }
        }
        __syncthreads();
    }
}

__global__ void vq_final_kernel(const int* __restrict__ counts,
                                const double* __restrict__ loss_sum,
                                float* __restrict__ out) {
    __shared__ double red[16];
    const int t = threadIdx.x;           // 1024 threads
    float p = (float)counts[t] / (float)N_ROWS;
    double term = (double)p * log((double)p + 1e-10);
#pragma unroll
    for (int off = 32; off > 0; off >>= 1) term += __shfl_down(term, off);
    if ((t & 63) == 0) red[t >> 6] = term;
    __syncthreads();
    if (t == 0) {
        double s = 0.0;
#pragma unroll
        for (int w = 0; w < 16; ++w) s += red[w];
        const size_t base = (size_t)N_ROWS * DIM;
        out[base]     = (float)(1.5 * (*loss_sum) / (double)((size_t)N_ROWS * DIM));
        out[base + 1] = (float)exp(-s);
    }
}

extern "C" void kernel_launch(void* const* d_in, const int* in_sizes, int n_in,
                              void* d_out, int out_size, void* d_ws, size_t ws_size,
                              hipStream_t stream) {
    const float* x   = (const float*)d_in[0];
    const float* emb = (const float*)d_in[1];
    float* out = (float*)d_out;

    char* ws = (char*)d_ws;
    double* loss_sum = (double*)ws;
    u32*  flagcnt  = (u32*)(ws + WS_FLAGCNT_OFF);
    int*  counts   = (int*)(ws + WS_COUNTS_OFF);
    float* bn      = (float*)(ws + WS_BN_OFF);
    float* nbs     = (float*)(ws + WS_NBS_OFF);
    char* Bc       = ws + WS_BC_OFF;
    u32*  flist    = (u32*)(ws + WS_FLIST_OFF);

    hipMemsetAsync(d_ws, 0, WS_ZERO_BYTES, stream);

    vq_prep<<<KCODES / 256, 256, 0, stream>>>(emb, bn, nbs, Bc);
    vq_screen<<<N_ROWS / 128, 512, 0, stream>>>(x, Bc, nbs, emb, out,
                                                counts, loss_sum, flagcnt, flist);
    vq_rescan<<<RS_GRID, 256, 0, stream>>>(x, emb, bn, flagcnt, flist,
                                           out, counts, loss_sum);
    vq_final_kernel<<<1, 1024, 0, stream>>>(counts, loss_sum, out);
}

// Round 13
// 226.976 us; speedup vs baseline: 1.0055x; 1.0055x over previous
//
#include <hip/hip_runtime.h>
#include <math.h>

#define N_ROWS (32 * 64 * 64)   // 131072 rows
#define KCODES 1024
#define DIM 64
#define NCHUNK 16               // 64 codes per chunk, 16 KB per chunk (hi+lo)

typedef __attribute__((ext_vector_type(8))) _Float16 f16x8;
typedef __attribute__((ext_vector_type(4))) float f32x4;
typedef unsigned long long u64;
typedef unsigned int u32;

// d_ws layout:
//   0       double loss_sum
//   8       u32 flag_count
//   16      int counts[1024]            (-> 4112) [zeroed]
//   4352    float bn[1024]              exact chain norms
//   8448    float nbs[1024]             1536 + 128*bn (fp32)
//   16384   char Bc[16][16384]          per 64-code chunk, gload-linear order:
//                                       hi [0,8K): off = tt*2048 + ks*1024 + (g*16+cl)*16 + j*2
//                                       lo [8K,16K): same
//   278528  u32 flaglist[N_ROWS]
#define WS_FLAGCNT_OFF 8
#define WS_COUNTS_OFF  16
#define WS_BN_OFF      4352
#define WS_NBS_OFF     8448
#define WS_BC_OFF      16384
#define WS_FLIST_OFF   278528
#define WS_ZERO_BYTES  4112

__device__ inline void gload_lds16(const void* g, void* l) {
    __builtin_amdgcn_global_load_lds(
        (const __attribute__((address_space(1))) unsigned int*)g,
        (__attribute__((address_space(3))) unsigned int*)l,
        16, 0, 0);
}

// ---------- prep: exact bn, C-init consts, 16x16-fragment-order split codes
__global__ void vq_prep(const float* __restrict__ emb,
                        float* __restrict__ bn,
                        float* __restrict__ nbs,
                        char* __restrict__ Bc) {
    int c = blockIdx.x * 256 + threadIdx.x;   // 4 blocks x 256 = 1024 codes
    const float* e = emb + (size_t)c * DIM;
    float s = 0.f;
#pragma unroll
    for (int d = 0; d < DIM; ++d) s = fmaf(e[d], e[d], s);
    bn[c] = s;
    nbs[c] = fmaf(s, 128.0f, 1536.0f);

    const int ch = c >> 6, tt = (c >> 4) & 3, cl = c & 15;
    char* dst = Bc + (size_t)ch * 16384;
#pragma unroll
    for (int ks = 0; ks < 2; ++ks)
#pragma unroll
        for (int g = 0; g < 4; ++g) {
            f16x8 ph, pl;
#pragma unroll
            for (int j = 0; j < 8; ++j) {
                float v = e[ks * 32 + g * 8 + j] * 256.0f;
                _Float16 hh = (_Float16)v;
                ph[j] = hh;
                pl[j] = (_Float16)(v - (float)hh);
            }
            const int off = tt * 2048 + ks * 1024 + (g * 16 + cl) * 16;
            *(f16x8*)(dst + off)        = ph;
            *(f16x8*)(dst + 8192 + off) = pl;
        }
}

// async copy chunk c into LDS buffer b: 2 x (512 threads x 16B) = 16 KB
#define STAGE(b, c) do {                                                  \
    const char* _g = Bc + (size_t)(c) * 16384 + tid * 16;                 \
    char* _l = &LB[b][(tid >> 6) * 1024];   /* wave-uniform base */       \
    gload_lds16(_g,        _l);                                           \
    gload_lds16(_g + 8192, _l + 8192);                                    \
} while (0)

// ---------- screen: 8-wave blocks, 16 rows/wave via mfma 16x16x32.
// v = nb + 256*(-dot) computed as 3 INDEPENDENT MFMA chains (ah*vh, ah*vl,
// al*vh) summed in the epilogue -> short dep chains, zero-init (no memory
// dep on chain head). nb served from LDS. Positive v -> u32 bit-min argmin.
__launch_bounds__(512, 2)
__global__ void vq_screen(const float* __restrict__ x,
                          const char* __restrict__ Bc,
                          const float* __restrict__ nbs,
                          const float* __restrict__ emb,
                          float* __restrict__ out,
                          int* __restrict__ counts,
                          double* __restrict__ loss_sum,
                          u32* __restrict__ flagcnt,
                          u32* __restrict__ flaglist) {
    __shared__ __align__(16) char LB[2][16384];
    __shared__ float NB[KCODES];   // 4 KB

    const int tid  = threadIdx.x;
    const int lane = tid & 63;
    const int wid  = tid >> 6;           // 8 waves x 16 rows = 128 rows/block
    const int cl = lane & 15;            // col slot (codes) / x-row for loads
    const int g  = lane >> 4;            // k-group 0..3
    const int rbase = blockIdx.x * 128 + wid * 16;
    const int myrow = rbase + cl;        // row whose x-elements this lane loads

    // A fragments: lane l, step ks, slot j = -x[myrow][ks*32 + g*8 + j]
    f16x8 ah0, ah1, al0, al1;
    float anp = 0.f;
    {
        const float* xp = x + (size_t)myrow * DIM + g * 8;
#pragma unroll
        for (int ks = 0; ks < 2; ++ks) {
            float4 u0 = *(const float4*)(xp + ks * 32);
            float4 u1 = *(const float4*)(xp + ks * 32 + 4);
            float v[8] = {u0.x, u0.y, u0.z, u0.w, u1.x, u1.y, u1.z, u1.w};
            f16x8 h8, l8;
#pragma unroll
            for (int j = 0; j < 8; ++j) {
                anp = fmaf(v[j], v[j], anp);
                float nv = -v[j];
                _Float16 hh = (_Float16)nv;
                h8[j] = hh;
                l8[j] = (_Float16)(nv - (float)hh);
            }
            if (ks == 0) { ah0 = h8; al0 = l8; }
            else         { ah1 = h8; al1 = l8; }
        }
    }
    // an[row=cl], replicated across the 4 k-groups
    anp += __shfl_xor(anp, 16);
    anp += __shfl_xor(anp, 32);
    const float an = anp;

    // stage nbs into LDS once (covered by the prologue barrier)
    NB[tid]       = nbs[tid];
    NB[tid + 512] = nbs[tid + 512];

    u32 best[4], sec[4], bcol[4];
#pragma unroll
    for (int r = 0; r < 4; ++r) {
        best[r] = 0xFFFFFFFFu; sec[r] = 0xFFFFFFFFu; bcol[r] = 0u;
    }

    STAGE(0, 0);
    __syncthreads();

    for (int c = 0; c < NCHUNK; ++c) {
        const int b = c & 1;
        if (c + 1 < NCHUNK) STAGE(b ^ 1, c + 1);   // overlap with compute
        const char* base = LB[b];

#pragma unroll
        for (int tt = 0; tt < 4; ++tt) {
            const float nb = NB[c * 64 + tt * 16 + cl];   // LDS broadcast
            f32x4 accA = {0.f, 0.f, 0.f, 0.f};
            f32x4 accB = {0.f, 0.f, 0.f, 0.f};
            f32x4 accC = {0.f, 0.f, 0.f, 0.f};
            {
                const int off = tt * 2048 + lane * 16;
                f16x8 vh = *(const f16x8*)(base + off);
                f16x8 vl = *(const f16x8*)(base + 8192 + off);
                accA = __builtin_amdgcn_mfma_f32_16x16x32_f16(ah0, vh, accA, 0, 0, 0);
                accB = __builtin_amdgcn_mfma_f32_16x16x32_f16(ah0, vl, accB, 0, 0, 0);
                accC = __builtin_amdgcn_mfma_f32_16x16x32_f16(al0, vh, accC, 0, 0, 0);
            }
            {
                const int off = tt * 2048 + 1024 + lane * 16;
                f16x8 vh = *(const f16x8*)(base + off);
                f16x8 vl = *(const f16x8*)(base + 8192 + off);
                accA = __builtin_amdgcn_mfma_f32_16x16x32_f16(ah1, vh, accA, 0, 0, 0);
                accB = __builtin_amdgcn_mfma_f32_16x16x32_f16(ah1, vl, accB, 0, 0, 0);
                accC = __builtin_amdgcn_mfma_f32_16x16x32_f16(al1, vh, accC, 0, 0, 0);
            }
            const u32 tl = (u32)(c * 64 + tt * 16 + cl);
#pragma unroll
            for (int r = 0; r < 4; ++r) {
                float v = nb + ((accB[r] + accC[r]) + accA[r]);
                u32 vb = __float_as_uint(v);       // positive -> monotone bits
                u32 mx = vb > best[r] ? vb : best[r];
                sec[r] = min(sec[r], mx);
                bool lt = vb < best[r];            // strict: first index wins
                bcol[r] = lt ? tl : bcol[r];
                best[r] = min(best[r], vb);
            }
        }
        __syncthreads();   // next chunk staged + all waves done with buf b
    }

    // reduce across the 16 col-lanes of each k-group (masks 1,2,4,8)
    u64 bp[4];
#pragma unroll
    for (int r = 0; r < 4; ++r) bp[r] = ((u64)best[r] << 32) | bcol[r];
#pragma unroll
    for (int m = 1; m < 16; m <<= 1) {
#pragma unroll
        for (int r = 0; r < 4; ++r) {
            u64 o  = __shfl_xor(bp[r], m);
            u32 os = __shfl_xor(sec[r], m);
            u32 oh = (u32)(o >> 32);
            u32 mh = (u32)(bp[r] >> 32);
            u32 mx = mh > oh ? mh : oh;
            sec[r] = min(min(sec[r], os), mx);
            if (o < bp[r]) bp[r] = o;
        }
    }

    // certify/gather: r-slot r of group g = row g*4+r; 64 lanes write 4 rows
    double dsum = 0.0;
#pragma unroll
    for (int r = 0; r < 4; ++r) {
        const int rowl = g * 4 + r;
        const int grow = rbase + rowl;
        const float bv = __uint_as_float((u32)(bp[r] >> 32));
        const u32 col = (u32)bp[r];
        const float sv = __uint_as_float(sec[r]);
        const float anr = __shfl(an, (lane & 48) | rowl);
        const float gap = sv - bv;
        const float T = fmaf(1e-4f, anr, 0.004f);
        const bool flg = (gap <= T) || (anr < 4.0f) || (anr > 5000.0f);
        if (!flg) {
            float4 q = *(const float4*)(emb + (size_t)col * DIM + cl * 4);
            *(float4*)(out + (size_t)grow * DIM + cl * 4) = q;
            if (cl == 0) {
                atomicAdd(&counts[col], 1);
                // loss identity: dist = an + bn - 2 dot = (acc-1536)/128 + an
                float dist = fmaxf(fmaf(bv - 1536.0f, 0.0078125f, anr), 0.f);
                dsum += (double)dist;
            }
        } else if (cl == 0) {
            u32 idx = atomicAdd(flagcnt, 1u);
            flaglist[idx] = (u32)grow;
        }
    }
    dsum += __shfl_xor(dsum, 16);
    dsum += __shfl_xor(dsum, 32);
    if (lane == 0) atomicAdd(loss_sum, dsum);
}

// ---------- rescan: block-per-flagged-row, exact fp32 argmin (R1 chains)
#define RS_GRID 4096
__launch_bounds__(256)
__global__ void vq_rescan(const float* __restrict__ x,
                          const float* __restrict__ emb,
                          const float* __restrict__ bn,
                          const u32* __restrict__ flagcnt,
                          const u32* __restrict__ flaglist,
                          float* __restrict__ out,
                          int* __restrict__ counts,
                          double* __restrict__ loss_sum) {
    __shared__ float Xs[DIM];
    __shared__ u64 wred[4];
    const u32 n = *flagcnt;
    const int t = threadIdx.x;

    for (u32 i = blockIdx.x; i < n; i += RS_GRID) {
        const int row = (int)flaglist[i];
        if (t < DIM) Xs[t] = x[(size_t)row * DIM + t];
        __syncthreads();

        float an = 0.f;
#pragma unroll
        for (int d = 0; d < DIM; ++d) an = fmaf(Xs[d], Xs[d], an);

        u64 bestp = ~0ull;
#pragma unroll
        for (int cc = 0; cc < 4; ++cc) {
            const int k = cc * 256 + t;
            const float* ek = emb + (size_t)k * DIM;
            float q0 = 0.f, q1 = 0.f, q2 = 0.f, q3 = 0.f;
#pragma unroll
            for (int d = 0; d < DIM; d += 4) {
                float4 ev = *(const float4*)(ek + d);
                q0 = fmaf(Xs[d],     ev.x, q0);
                q1 = fmaf(Xs[d + 1], ev.y, q1);
                q2 = fmaf(Xs[d + 2], ev.z, q2);
                q3 = fmaf(Xs[d + 3], ev.w, q3);
            }
            float dot = (q0 + q1) + (q2 + q3);
            float dist = fmaxf((an + bn[k]) - 2.0f * dot, 0.f);
            u64 p = ((u64)__float_as_uint(dist) << 32) | (u32)k;
            if (p < bestp) bestp = p;
        }
#pragma unroll
        for (int m = 1; m < 64; m <<= 1) {
            u64 o = __shfl_xor(bestp, m);
            if (o < bestp) bestp = o;
        }
        if ((t & 63) == 0) wred[t >> 6] = bestp;
        __syncthreads();
        u64 b = wred[0];
        if (wred[1] < b) b = wred[1];
        if (wred[2] < b) b = wred[2];
        if (wred[3] < b) b = wred[3];
        const int bk = (int)(u32)b;

        if (t < DIM) {
            float qv = emb[(size_t)bk * DIM + t];
            out[(size_t)row * DIM + t] = qv;
            float dx = qv - Xs[t];
            double ds = (double)(dx * dx);
#pragma unroll
            for (int m = 1; m < 64; m <<= 1) ds += __shfl_xor(ds, m);
            if (t == 0) {
                atomicAdd(loss_sum, ds);
                atomicAdd(&counts[bk], 1);
            }
        }
        __syncthreads();
    }
}

__global__ void vq_final_kernel(const int* __restrict__ counts,
                                const double* __restrict__ loss_sum,
                                float* __restrict__ out) {
    __shared__ double red[16];
    const int t = threadIdx.x;           // 1024 threads
    float p = (float)counts[t] / (float)N_ROWS;
    double term = (double)p * log((double)p + 1e-10);
#pragma unroll
    for (int off = 32; off > 0; off >>= 1) term += __shfl_down(term, off);
    if ((t & 63) == 0) red[t >> 6] = term;
    __syncthreads();
    if (t == 0) {
        double s = 0.0;
#pragma unroll
        for (int w = 0; w < 16; ++w) s += red[w];
        const size_t base = (size_t)N_ROWS * DIM;
        out[base]     = (float)(1.5 * (*loss_sum) / (double)((size_t)N_ROWS * DIM));
        out[base + 1] = (float)exp(-s);
    }
}

extern "C" void kernel_launch(void* const* d_in, const int* in_sizes, int n_in,
                              void* d_out, int out_size, void* d_ws, size_t ws_size,
                              hipStream_t stream) {
    const float* x   = (const float*)d_in[0];
    const float* emb = (const float*)d_in[1];
    float* out = (float*)d_out;

    char* ws = (char*)d_ws;
    double* loss_sum = (double*)ws;
    u32*  flagcnt  = (u32*)(ws + WS_FLAGCNT_OFF);
    int*  counts   = (int*)(ws + WS_COUNTS_OFF);
    float* bn      = (float*)(ws + WS_BN_OFF);
    float* nbs     = (float*)(ws + WS_NBS_OFF);
    char* Bc       = ws + WS_BC_OFF;
    u32*  flist    = (u32*)(ws + WS_FLIST_OFF);

    hipMemsetAsync(d_ws, 0, WS_ZERO_BYTES, stream);

    vq_prep<<<KCODES / 256, 256, 0, stream>>>(emb, bn, nbs, Bc);
    vq_screen<<<N_ROWS / 128, 512, 0, stream>>>(x, Bc, nbs, emb, out,
                                                counts, loss_sum, flagcnt, flist);
    vq_rescan<<<RS_GRID, 256, 0, stream>>>(x, emb, bn, flagcnt, flist,
                                           out, counts, loss_sum);
    vq_final_kernel<<<1, 1024, 0, stream>>>(counts, loss_sum, out);
}